// Round 12
// baseline (267.173 us; speedup 1.0000x reference)
//
#include <hip/hip_runtime.h>

typedef __bf16 bf16x8 __attribute__((ext_vector_type(8)));
typedef __bf16 bf16x4 __attribute__((ext_vector_type(4)));
typedef float f32x4 __attribute__((ext_vector_type(4)));
typedef unsigned short us8 __attribute__((ext_vector_type(8)));
typedef unsigned short us4 __attribute__((ext_vector_type(4)));
typedef short sh4 __attribute__((ext_vector_type(4)));

#define SCALE_Q 0.17677669529663687f  // 32^-0.5

__device__ __forceinline__ unsigned short f2b(float f) {
    __bf16 h = (__bf16)f;
    return __builtin_bit_cast(unsigned short, h);
}
__device__ __forceinline__ float b2f(unsigned short h) {
    union { unsigned u; float f; } v; v.u = ((unsigned)h) << 16;
    return v.f;
}
__device__ __forceinline__ f32x4 mfma16(us8 a, us8 b, f32x4 c) {
    return __builtin_amdgcn_mfma_f32_16x16x32_bf16(
        __builtin_bit_cast(bf16x8, a), __builtin_bit_cast(bf16x8, b), c, 0, 0, 0);
}

#if __has_builtin(__builtin_amdgcn_mfma_f32_16x16x16bf16_1k)
__device__ __forceinline__ f32x4 mfma16k16(us4 a, us4 b, f32x4 c) {
    return __builtin_amdgcn_mfma_f32_16x16x16bf16_1k(
        __builtin_bit_cast(sh4, a), __builtin_bit_cast(sh4, b), c, 0, 0, 0);
}
#elif __has_builtin(__builtin_amdgcn_mfma_f32_16x16x16_bf16)
__device__ __forceinline__ f32x4 mfma16k16(us4 a, us4 b, f32x4 c) {
    return __builtin_amdgcn_mfma_f32_16x16x16_bf16(
        __builtin_bit_cast(bf16x4, a), __builtin_bit_cast(bf16x4, b), c, 0, 0, 0);
}
#else
__device__ __forceinline__ f32x4 mfma16k16(us4 a, us4 b, f32x4 c) {
    asm volatile("v_mfma_f32_16x16x16_bf16 %0, %1, %2, %0"
                 : "+v"(c) : "v"(a), "v"(b));
    return c;
}
#endif

__device__ __forceinline__ us8 lds_ld8(const unsigned short* base, int byteoff) {
    return *(const us8*)((const char*)base + byteoff);
}
__device__ __forceinline__ void lds_st8(unsigned short* base, int byteoff, us8 v) {
    *(us8*)((char*)base + byteoff) = v;
}

// ---------- pack qkv weights into per-(wave,ct) fragment blocks, fold SCALE_Q ----------
__global__ void k_pack_qkvw(const float* __restrict__ qkv_w, unsigned short* __restrict__ dst) {
    int gid = blockIdx.x * 256 + threadIdx.x;          // 49152
    int blk = gid >> 9, rem = gid & 511;
    int lane = rem >> 3, j = rem & 7;
    int w = blk / 24, r1 = blk % 24, ct = r1 >> 2, kk = r1 & 3;
    int col = w * 96 + ct * 16 + (lane & 15);
    int k = kk * 32 + (lane >> 4) * 8 + j;
    float v = qkv_w[k * 384 + col];
    if (col < 128) v *= SCALE_Q;
    dst[gid] = f2b(v);
}
__global__ void k_scale_qkvb(const float* __restrict__ qkv_b, float* __restrict__ dst) {
    int i = blockIdx.x * 256 + threadIdx.x;
    if (i < 384) dst[i] = qkv_b[i] * (i < 128 ? SCALE_Q : 1.f);
}
__global__ void k_pack_projw(const float* __restrict__ proj_w, unsigned short* __restrict__ dst) {
    int gid = blockIdx.x * 256 + threadIdx.x;          // 16384
    int blk = gid >> 9, rem = gid & 511;
    int lane = rem >> 3, j = rem & 7;
    int w = blk >> 3, r1 = blk & 7, ct = r1 >> 2, kk = r1 & 3;
    int col = w * 32 + ct * 16 + (lane & 15);
    int k = kk * 32 + (lane >> 4) * 8 + j;
    dst[gid] = f2b(proj_w[k * 128 + col]);
}

// ---------- pack MLP weights: per ct-PAIR 16KB slices (layout verified r10/r11) ----------
__global__ void k_pack_mlp(const float* __restrict__ fc1_w, const float* __restrict__ fc2_w,
                           unsigned short* __restrict__ wPack) {
    int gid = blockIdx.x * 256 + threadIdx.x;          // 131072
    int pair = gid >> 13;
    int rem = gid & 8191;
    float v;
    if (rem < 4096) {
        int half = rem >> 11;
        int r2 = rem & 2047;
        int kk = r2 >> 9, r3 = r2 & 511;
        int lane = r3 >> 3, j = r3 & 7;
        int m = lane & 15;
        int col = pair * 32 + (m >> 2) * 8 + half * 4 + (m & 3);
        int k = kk * 32 + (lane >> 4) * 8 + j;
        v = fc1_w[(size_t)k * 512 + col];
    } else {
        int r2 = rem - 4096;
        int co = r2 >> 9, r3 = r2 & 511;
        int lane = r3 >> 3, j = r3 & 7;
        int k = pair * 32 + (lane >> 4) * 8 + j;
        v = fc2_w[(size_t)k * 128 + co * 16 + (lane & 15)];
    }
    wPack[gid] = f2b(v);
}

// =====================================================================
// FUSED: LN1 + roll/partition + QKV + attn + proj (+resid -> LDS x_mid)
//        + LN2 + FC1 + GELU + FC2 + resid -> final out. One kernel.
// Block = 4 waves = 4 windows = 64 tokens. LDS 64KB:
//   phases A-D: sm[4][12288B] QKV workspace (bytes [0,49152))
//   after D:    x_mid fp32 [64 rows][512B] swizzled  (bytes [0,32768))
//               LN scratch 4x4KB (bytes [32768,49152), pre-staging)
//               weight dbuf 2x16KB (bytes [32768,65536))
// =====================================================================
__global__ __launch_bounds__(256, 2) void k_fused(
    const float* __restrict__ x,
    const float* __restrict__ ln1s, const float* __restrict__ ln1b,
    const unsigned short* __restrict__ qkvWp, const float* __restrict__ qkvBs,
    const float* __restrict__ relb,
    const unsigned short* __restrict__ projWp, const float* __restrict__ projB,
    const float* __restrict__ ln2s, const float* __restrict__ ln2b,
    const unsigned short* __restrict__ wPack,
    const float* __restrict__ fc1B, const float* __restrict__ fc2B,
    float* __restrict__ out)
{
    __shared__ unsigned short smem[32768];   // 64 KB
    __shared__ float sbias[196];
    unsigned short* sm = smem;
    const int tid = threadIdx.x;
    const int wave = tid >> 6, lane = tid & 63;
    const int g = lane >> 4, m16 = lane & 15;
    if (tid < 196) sbias[tid] = relb[tid];
    const int win0 = blockIdx.x * 4;
    const int winM = win0 + wave;
    const int bbM = winM >> 8, whM = (winM >> 4) & 15, wnM = winM & 15;

    // ---- phase A: LN1 + roll-gather -> A-tile [16][256B], XOR-swizzled ----
    {
        float4 sc0 = *(const float4*)(ln1s + m16 * 8);
        float4 sc1 = *(const float4*)(ln1s + m16 * 8 + 4);
        float4 bi0 = *(const float4*)(ln1b + m16 * 8);
        float4 bi1 = *(const float4*)(ln1b + m16 * 8 + 4);
        #pragma unroll
        for (int it = 0; it < 4; ++it) {
            int tok = it * 4 + g;
            int ti = tok >> 2, tj = tok & 3;
            int hh = (whM * 4 + ti + 2) & 63, ww = (wnM * 4 + tj + 2) & 63;
            const float* xr = x + ((((size_t)bbM << 12) | (hh << 6) | ww) * 128) + m16 * 8;
            float4 v0 = *(const float4*)xr, v1 = *(const float4*)(xr + 4);
            float sum = v0.x + v0.y + v0.z + v0.w + v1.x + v1.y + v1.z + v1.w;
            float sq  = v0.x*v0.x + v0.y*v0.y + v0.z*v0.z + v0.w*v0.w
                      + v1.x*v1.x + v1.y*v1.y + v1.z*v1.z + v1.w*v1.w;
            #pragma unroll
            for (int m = 1; m < 16; m <<= 1) { sum += __shfl_xor(sum, m); sq += __shfl_xor(sq, m); }
            float mu = sum * 0.0078125f;
            float rstd = rsqrtf(sq * 0.0078125f - mu * mu + 1e-6f);
            us8 o;
            o[0] = f2b((v0.x - mu) * rstd * sc0.x + bi0.x);
            o[1] = f2b((v0.y - mu) * rstd * sc0.y + bi0.y);
            o[2] = f2b((v0.z - mu) * rstd * sc0.z + bi0.z);
            o[3] = f2b((v0.w - mu) * rstd * sc0.w + bi0.w);
            o[4] = f2b((v1.x - mu) * rstd * sc1.x + bi1.x);
            o[5] = f2b((v1.y - mu) * rstd * sc1.y + bi1.y);
            o[6] = f2b((v1.z - mu) * rstd * sc1.z + bi1.z);
            o[7] = f2b((v1.w - mu) * rstd * sc1.w + bi1.w);
            lds_st8(sm, wave * 12288 + tok * 256 + ((m16 * 16) ^ ((tok & 7) << 4)), o);
        }
    }
    __syncthreads();

    us8 afr[4][4];
    #pragma unroll
    for (int w = 0; w < 4; ++w)
        #pragma unroll
        for (int k = 0; k < 4; ++k)
            afr[w][k] = lds_ld8(sm, w * 12288 + m16 * 256 + ((k * 64 + g * 16) ^ ((m16 & 7) << 4)));
    __syncthreads();

    // ---- phase B: QKV GEMM, cols split by wave, packed coalesced B-frags ----
    #pragma unroll
    for (int ct = 0; ct < 6; ++ct) {
        const unsigned short* bp = qkvWp + (size_t)((wave * 6 + ct) * 4) * 512 + lane * 8;
        us8 b0 = *(const us8*)(bp);
        us8 b1 = *(const us8*)(bp + 512);
        us8 b2 = *(const us8*)(bp + 1024);
        us8 b3 = *(const us8*)(bp + 1536);
        f32x4 acc[4] = {{0.f,0.f,0.f,0.f},{0.f,0.f,0.f,0.f},{0.f,0.f,0.f,0.f},{0.f,0.f,0.f,0.f}};
        #pragma unroll
        for (int w = 0; w < 4; ++w) {
            acc[w] = mfma16(afr[w][0], b0, acc[w]);
            acc[w] = mfma16(afr[w][1], b1, acc[w]);
            acc[w] = mfma16(afr[w][2], b2, acc[w]);
            acc[w] = mfma16(afr[w][3], b3, acc[w]);
        }
        const int c = wave * 96 + ct * 16 + m16;
        const float bias = qkvBs[c];
        const int s = c >> 7;
        const int rem = c & 127, hq = rem >> 5, hd = rem & 31;
        #pragma unroll
        for (int w = 0; w < 4; ++w) {
            const int base = w * 12288;
            if (s == 2) {
                us4 pk;
                #pragma unroll
                for (int jj = 0; jj < 4; ++jj) pk[jj] = f2b(acc[w][jj] + bias);
                *(us4*)((char*)sm + base + 8192 + hq * 1024 + hd * 32
                        + ((g ^ ((hd >> 2) & 3)) << 3)) = pk;
            } else {
                #pragma unroll
                for (int jj = 0; jj < 4; ++jj) {
                    int tok = g * 4 + jj;
                    int chunk = (hd >> 3) ^ ((tok >> 1) & 3);
                    *(unsigned short*)((char*)sm + base + s * 4096 + hq * 1024
                                       + tok * 64 + chunk * 16 + (hd & 7) * 2)
                        = f2b(acc[w][jj] + bias);
                }
            }
        }
    }
    __syncthreads();

    // ---- phase C: attention via MFMA (wave-local window) ----
    {
        const int base = wave * 12288;
        const int ti = m16 >> 2, tj = m16 & 3;
        const int hhq = whM * 4 + ti, wwq = wnM * 4 + tj;
        const int myid = (hhq < 60 ? 0 : (hhq < 62 ? 3 : 6)) + (wwq < 60 ? 0 : (wwq < 62 ? 1 : 2));
        const int qkswz = (g ^ ((m16 >> 1) & 3)) * 16;
        const int vswz  = (g ^ ((m16 >> 2) & 3)) << 3;
        f32x4 po[4][2];
        #pragma unroll
        for (int h = 0; h < 4; ++h) {
            us8 kf = lds_ld8(sm, base + 4096 + h * 1024 + m16 * 64 + qkswz);
            us8 qf = lds_ld8(sm, base +        h * 1024 + m16 * 64 + qkswz);
            f32x4 st = mfma16(kf, qf, (f32x4){0.f,0.f,0.f,0.f});
            float p[4];
            #pragma unroll
            for (int jj = 0; jj < 4; ++jj) {
                int kk = g * 4 + jj;
                int pi = kk >> 2, pj = kk & 3;
                int hhk = whM * 4 + pi, wwk = wnM * 4 + pj;
                int pid = (hhk < 60 ? 0 : (hhk < 62 ? 3 : 6)) + (wwk < 60 ? 0 : (wwk < 62 ? 1 : 2));
                float v = st[jj] + sbias[((ti - pi + 3) * 7 + (tj - pj + 3)) * 4 + h];
                p[jj] = (pid != myid) ? v - 100.f : v;
            }
            #pragma unroll
            for (int rep = 0; rep < 2; ++rep) {   // double softmax (faithful)
                float mx = fmaxf(fmaxf(p[0], p[1]), fmaxf(p[2], p[3]));
                mx = fmaxf(mx, __shfl_xor(mx, 16));
                mx = fmaxf(mx, __shfl_xor(mx, 32));
                float ssum = 0.f;
                #pragma unroll
                for (int jj = 0; jj < 4; ++jj) { p[jj] = __expf(p[jj] - mx); ssum += p[jj]; }
                ssum += __shfl_xor(ssum, 16);
                ssum += __shfl_xor(ssum, 32);
                float inv = 1.f / ssum;
                #pragma unroll
                for (int jj = 0; jj < 4; ++jj) p[jj] *= inv;
            }
            us4 pf;
            #pragma unroll
            for (int jj = 0; jj < 4; ++jj) pf[jj] = f2b(p[jj]);
            #pragma unroll
            for (int dh = 0; dh < 2; ++dh) {
                us4 vf = *(const us4*)((const char*)sm + base + 8192 + h * 1024
                                       + (dh * 16 + m16) * 32 + vswz);
                po[h][dh] = mfma16k16(vf, pf, (f32x4){0.f,0.f,0.f,0.f});
            }
        }
        #pragma unroll
        for (int h = 0; h < 4; ++h)
            #pragma unroll
            for (int dh = 0; dh < 2; ++dh) {
                us4 pk;
                #pragma unroll
                for (int jj = 0; jj < 4; ++jj) pk[jj] = f2b(po[h][dh][jj]);
                *(us4*)((char*)sm + base + m16 * 256
                        + ((h * 64 + dh * 32 + g * 8) ^ ((m16 & 7) << 4))) = pk;
            }
    }
    __syncthreads();

    // ---- phase D: proj + residual -> x_mid fp32 LDS tile (NOT global) ----
    {
        us8 cfr[4][4];
        #pragma unroll
        for (int w = 0; w < 4; ++w)
            #pragma unroll
            for (int k = 0; k < 4; ++k)
                cfr[w][k] = lds_ld8(sm, w * 12288 + m16 * 256 + ((k * 64 + g * 16) ^ ((m16 & 7) << 4)));
        __syncthreads();        // all cfr hoisted; QKV workspace now dead -> x_mid may overwrite
        #pragma unroll
        for (int ct = 0; ct < 2; ++ct) {
            const unsigned short* bp = projWp + (size_t)((wave * 2 + ct) * 4) * 512 + lane * 8;
            us8 b0 = *(const us8*)(bp);
            us8 b1 = *(const us8*)(bp + 512);
            us8 b2 = *(const us8*)(bp + 1024);
            us8 b3 = *(const us8*)(bp + 1536);
            const int c = wave * 32 + ct * 16 + m16;
            const float pb = projB[c];
            #pragma unroll
            for (int w = 0; w < 4; ++w) {
                f32x4 acc = {0.f, 0.f, 0.f, 0.f};
                acc = mfma16(cfr[w][0], b0, acc);
                acc = mfma16(cfr[w][1], b1, acc);
                acc = mfma16(cfr[w][2], b2, acc);
                acc = mfma16(cfr[w][3], b3, acc);
                const int winw = win0 + w;
                const int bb = winw >> 8, wh = (winw >> 4) & 15, wn = winw & 15;
                #pragma unroll
                for (int jj = 0; jj < 4; ++jj) {
                    int tok = g * 4 + jj;
                    int hh3 = (wh * 4 + (tok >> 2) + 2) & 63;
                    int ww3 = (wn * 4 + (tok & 3) + 2) & 63;
                    size_t t = (((size_t)bb << 12) | (hh3 << 6) | ww3);
                    float xm = acc[jj] + pb + x[t * 128 + c];
                    *(float*)((char*)smem + (w * 16 + tok) * 512
                              + ((c * 4) ^ ((tok & 7) << 4))) = xm;
                }
            }
        }
    }
    __syncthreads();            // x_mid tile complete (all waves, all cols)

    // ---- LN2 on this wave's 16 rows (window = wave), from x_mid LDS ----
    unsigned short* scr = (unsigned short*)((char*)smem + 32768 + wave * 4096);
    {
        float4 sc0 = *(const float4*)(ln2s + m16 * 8);
        float4 sc1 = *(const float4*)(ln2s + m16 * 8 + 4);
        float4 bi0 = *(const float4*)(ln2b + m16 * 8);
        float4 bi1 = *(const float4*)(ln2b + m16 * 8 + 4);
        #pragma unroll
        for (int it = 0; it < 4; ++it) {
            int r = it * 4 + g;                       // row within window
            const char* xmrow = (const char*)smem + (wave * 16 + r) * 512;
            int swz = (r & 7) << 4;
            float4 v0 = *(const float4*)(xmrow + ((m16 * 32) ^ swz));
            float4 v1 = *(const float4*)(xmrow + ((m16 * 32 + 16) ^ swz));
            float sum = v0.x + v0.y + v0.z + v0.w + v1.x + v1.y + v1.z + v1.w;
            float sq  = v0.x*v0.x + v0.y*v0.y + v0.z*v0.z + v0.w*v0.w
                      + v1.x*v1.x + v1.y*v1.y + v1.z*v1.z + v1.w*v1.w;
            #pragma unroll
            for (int m = 1; m < 16; m <<= 1) { sum += __shfl_xor(sum, m); sq += __shfl_xor(sq, m); }
            float mu = sum * 0.0078125f;
            float rstd = rsqrtf(sq * 0.0078125f - mu * mu + 1e-6f);
            us8 o;
            o[0] = f2b((v0.x - mu) * rstd * sc0.x + bi0.x);
            o[1] = f2b((v0.y - mu) * rstd * sc0.y + bi0.y);
            o[2] = f2b((v0.z - mu) * rstd * sc0.z + bi0.z);
            o[3] = f2b((v0.w - mu) * rstd * sc0.w + bi0.w);
            o[4] = f2b((v1.x - mu) * rstd * sc1.x + bi1.x);
            o[5] = f2b((v1.y - mu) * rstd * sc1.y + bi1.y);
            o[6] = f2b((v1.z - mu) * rstd * sc1.z + bi1.z);
            o[7] = f2b((v1.w - mu) * rstd * sc1.w + bi1.w);
            lds_st8(scr, r * 256 + ((m16 * 16) ^ ((r & 7) << 4)), o);
        }
    }
    us8 bx[4];
    #pragma unroll
    for (int kk = 0; kk < 4; ++kk)
        bx[kk] = lds_ld8(scr, m16 * 256 + ((kk * 64 + g * 16) ^ ((m16 & 7) << 4)));
    __syncthreads();            // LN scratch dead -> weight staging may overwrite

    // ---- stage MLP pair 0 into buf0 (bytes [32768,49152)) ----
    #pragma unroll
    for (int sub = 0; sub < 4; ++sub) {
        const unsigned short* src = wPack + sub * 2048 + tid * 8;
        unsigned short* dst = &smem[16384 + sub * 2048 + wave * 512];
#if __has_builtin(__builtin_amdgcn_global_load_lds)
        __builtin_amdgcn_global_load_lds(
            (const __attribute__((address_space(1))) void*)src,
            (__attribute__((address_space(3))) void*)dst, 16, 0, 0);
#else
        *(us8*)(dst + lane * 8) = *(const us8*)src;
#endif
    }
    __syncthreads();

    f32x4 accO[8];
    #pragma unroll
    for (int co = 0; co < 8; ++co) accO[co] = (f32x4){0.f, 0.f, 0.f, 0.f};

    for (int p = 0; p < 16; ++p) {
        if (p < 15) {
            #pragma unroll
            for (int sub = 0; sub < 4; ++sub) {
                const unsigned short* src = wPack + (p + 1) * 8192 + sub * 2048 + tid * 8;
                unsigned short* dst = &smem[16384 + ((p + 1) & 1) * 8192 + sub * 2048 + wave * 512];
#if __has_builtin(__builtin_amdgcn_global_load_lds)
                __builtin_amdgcn_global_load_lds(
                    (const __attribute__((address_space(1))) void*)src,
                    (__attribute__((address_space(3))) void*)dst, 16, 0, 0);
#else
                *(us8*)(dst + lane * 8) = *(const us8*)src;
#endif
            }
        }
        const char* wb = (const char*)&smem[16384 + (p & 1) * 8192];
        // FC1^T halves: hA cols p*32+g*8+jj, hB cols p*32+g*8+4+jj (row = wave*16+m16)
        f32x4 hA = {0.f, 0.f, 0.f, 0.f}, hB = {0.f, 0.f, 0.f, 0.f};
        #pragma unroll
        for (int kk = 0; kk < 4; ++kk) {
            hA = mfma16(*(const us8*)(wb + kk * 1024 + lane * 16), bx[kk], hA);
            hB = mfma16(*(const us8*)(wb + 4096 + kk * 1024 + lane * 16), bx[kk], hB);
        }
        float4 bA = *(const float4*)(fc1B + p * 32 + g * 8);
        float4 bB = *(const float4*)(fc1B + p * 32 + g * 8 + 4);
        us8 pa;
        #pragma unroll
        for (int jj = 0; jj < 4; ++jj) {
            float v = hA[jj] + ((const float*)&bA)[jj];
            float z = v + 0.044715f * v * v * v;
            pa[jj] = f2b(v * __builtin_amdgcn_rcpf(1.f + __builtin_amdgcn_exp2f(-2.3022082f * z)));
            float w = hB[jj] + ((const float*)&bB)[jj];
            float y = w + 0.044715f * w * w * w;
            pa[4 + jj] = f2b(w * __builtin_amdgcn_rcpf(1.f + __builtin_amdgcn_exp2f(-2.3022082f * y)));
        }
        // FC2: 8 full-rate K=32 MFMAs
        #pragma unroll
        for (int co = 0; co < 8; ++co) {
            us8 bw = *(const us8*)(wb + 8192 + co * 1024 + lane * 16);
            accO[co] = mfma16(pa, bw, accO[co]);
        }
        __syncthreads();
    }

    // ---- epilogue: bias + LDS residual + window-reverse scatter -> final out ----
    {
        const int winw = win0 + wave;
        const int bb = winw >> 8, wh = (winw >> 4) & 15, wn = winw & 15;
        #pragma unroll
        for (int co = 0; co < 8; ++co) {
            int col = co * 16 + m16;
            float b2v = fc2B[col];
            #pragma unroll
            for (int jj = 0; jj < 4; ++jj) {
                int tok = g * 4 + jj;
                float xm = *(const float*)((const char*)smem + (wave * 16 + tok) * 512
                                           + ((col * 4) ^ ((tok & 7) << 4)));
                int hh3 = (wh * 4 + (tok >> 2) + 2) & 63;
                int ww3 = (wn * 4 + (tok & 3) + 2) & 63;
                size_t t = (((size_t)bb << 12) | (hh3 << 6) | ww3);
                out[t * 128 + col] = accO[co][jj] + b2v + xm;
            }
        }
    }
}

// ---------- launch ----------
extern "C" void kernel_launch(void* const* d_in, const int* in_sizes, int n_in,
                              void* d_out, int out_size, void* d_ws, size_t ws_size,
                              hipStream_t stream) {
    const float* x        = (const float*)d_in[0];
    const float* ln1_s    = (const float*)d_in[1];
    const float* ln1_b    = (const float*)d_in[2];
    const float* qkv_w    = (const float*)d_in[3];
    const float* qkv_b    = (const float*)d_in[4];
    const float* rel_bias = (const float*)d_in[5];
    const float* proj_w   = (const float*)d_in[6];
    const float* proj_b   = (const float*)d_in[7];
    const float* ln2_s    = (const float*)d_in[8];
    const float* ln2_b    = (const float*)d_in[9];
    const float* fc1_w    = (const float*)d_in[10];
    const float* fc1_b    = (const float*)d_in[11];
    const float* fc2_w    = (const float*)d_in[12];
    const float* fc2_b    = (const float*)d_in[13];
    float* out = (float*)d_out;
    char* ws = (char*)d_ws;

    unsigned short* qkv_wp  = (unsigned short*)(ws);             // 96KB packed qkv frags
    unsigned short* proj_wp = (unsigned short*)(ws + 98304);     // 32KB packed proj frags
    unsigned short* wpack   = (unsigned short*)(ws + 131072);    // 256KB packed MLP (16x16KB)
    float*          qkv_bs  = (float*)(ws + 393216);             // 1.5KB scaled qkv bias

    k_pack_qkvw<<<192, 256, 0, stream>>>(qkv_w, qkv_wp);
    k_scale_qkvb<<<2, 256, 0, stream>>>(qkv_b, qkv_bs);
    k_pack_projw<<<64, 256, 0, stream>>>(proj_w, proj_wp);
    k_pack_mlp<<<512, 256, 0, stream>>>(fc1_w, fc2_w, wpack);

    k_fused<<<4096, 256, 0, stream>>>(x, ln1_s, ln1_b, qkv_wp, qkv_bs, rel_bias,
                                      proj_wp, proj_b, ln2_s, ln2_b, wpack,
                                      fc1_b, fc2_b, out);
}

// Round 13
// 207.192 us; speedup vs baseline: 1.2895x; 1.2895x over previous
//
#include <hip/hip_runtime.h>

typedef __bf16 bf16x8 __attribute__((ext_vector_type(8)));
typedef __bf16 bf16x4 __attribute__((ext_vector_type(4)));
typedef float f32x4 __attribute__((ext_vector_type(4)));
typedef unsigned short us8 __attribute__((ext_vector_type(8)));
typedef unsigned short us4 __attribute__((ext_vector_type(4)));
typedef short sh4 __attribute__((ext_vector_type(4)));

#define SCALE_Q 0.17677669529663687f  // 32^-0.5

__device__ __forceinline__ unsigned short f2b(float f) {
    __bf16 h = (__bf16)f;
    return __builtin_bit_cast(unsigned short, h);
}
__device__ __forceinline__ float b2f(unsigned short h) {
    union { unsigned u; float f; } v; v.u = ((unsigned)h) << 16;
    return v.f;
}
__device__ __forceinline__ f32x4 mfma16(us8 a, us8 b, f32x4 c) {
    return __builtin_amdgcn_mfma_f32_16x16x32_bf16(
        __builtin_bit_cast(bf16x8, a), __builtin_bit_cast(bf16x8, b), c, 0, 0, 0);
}

#if __has_builtin(__builtin_amdgcn_mfma_f32_16x16x16bf16_1k)
__device__ __forceinline__ f32x4 mfma16k16(us4 a, us4 b, f32x4 c) {
    return __builtin_amdgcn_mfma_f32_16x16x16bf16_1k(
        __builtin_bit_cast(sh4, a), __builtin_bit_cast(sh4, b), c, 0, 0, 0);
}
#elif __has_builtin(__builtin_amdgcn_mfma_f32_16x16x16_bf16)
__device__ __forceinline__ f32x4 mfma16k16(us4 a, us4 b, f32x4 c) {
    return __builtin_amdgcn_mfma_f32_16x16x16_bf16(
        __builtin_bit_cast(bf16x4, a), __builtin_bit_cast(bf16x4, b), c, 0, 0, 0);
}
#else
__device__ __forceinline__ f32x4 mfma16k16(us4 a, us4 b, f32x4 c) {
    asm volatile("v_mfma_f32_16x16x16_bf16 %0, %1, %2, %0"
                 : "+v"(c) : "v"(a), "v"(b));
    return c;
}
#endif

__device__ __forceinline__ us8 lds_ld8(const unsigned short* base, int byteoff) {
    return *(const us8*)((const char*)base + byteoff);
}
__device__ __forceinline__ void lds_st8(unsigned short* base, int byteoff, us8 v) {
    *(us8*)((char*)base + byteoff) = v;
}

// ---------- pack qkv weights into per-(wave,ct) fragment blocks, fold SCALE_Q ----------
__global__ void k_pack_qkvw(const float* __restrict__ qkv_w, unsigned short* __restrict__ dst) {
    int gid = blockIdx.x * 256 + threadIdx.x;          // 49152
    int blk = gid >> 9, rem = gid & 511;
    int lane = rem >> 3, j = rem & 7;
    int w = blk / 24, r1 = blk % 24, ct = r1 >> 2, kk = r1 & 3;
    int col = w * 96 + ct * 16 + (lane & 15);
    int k = kk * 32 + (lane >> 4) * 8 + j;
    float v = qkv_w[k * 384 + col];
    if (col < 128) v *= SCALE_Q;
    dst[gid] = f2b(v);
}
__global__ void k_scale_qkvb(const float* __restrict__ qkv_b, float* __restrict__ dst) {
    int i = blockIdx.x * 256 + threadIdx.x;
    if (i < 384) dst[i] = qkv_b[i] * (i < 128 ? SCALE_Q : 1.f);
}
__global__ void k_pack_projw(const float* __restrict__ proj_w, unsigned short* __restrict__ dst) {
    int gid = blockIdx.x * 256 + threadIdx.x;          // 16384
    int blk = gid >> 9, rem = gid & 511;
    int lane = rem >> 3, j = rem & 7;
    int w = blk >> 3, r1 = blk & 7, ct = r1 >> 2, kk = r1 & 3;
    int col = w * 32 + ct * 16 + (lane & 15);
    int k = kk * 32 + (lane >> 4) * 8 + j;
    dst[gid] = f2b(proj_w[k * 128 + col]);
}

// ---------- pack MLP weights: per ct-PAIR 16KB slices (layout verified r10/r11) ----------
__global__ void k_pack_mlp(const float* __restrict__ fc1_w, const float* __restrict__ fc2_w,
                           unsigned short* __restrict__ wPack) {
    int gid = blockIdx.x * 256 + threadIdx.x;          // 131072
    int pair = gid >> 13;
    int rem = gid & 8191;
    float v;
    if (rem < 4096) {
        int half = rem >> 11;
        int r2 = rem & 2047;
        int kk = r2 >> 9, r3 = r2 & 511;
        int lane = r3 >> 3, j = r3 & 7;
        int m = lane & 15;
        int col = pair * 32 + (m >> 2) * 8 + half * 4 + (m & 3);
        int k = kk * 32 + (lane >> 4) * 8 + j;
        v = fc1_w[(size_t)k * 512 + col];
    } else {
        int r2 = rem - 4096;
        int co = r2 >> 9, r3 = r2 & 511;
        int lane = r3 >> 3, j = r3 & 7;
        int k = pair * 32 + (lane >> 4) * 8 + j;
        v = fc2_w[(size_t)k * 128 + co * 16 + (lane & 15)];
    }
    wPack[gid] = f2b(v);
}

// =====================================================================
// K1 v3: LN1 + roll + partition + QKV + attn + proj + residual.
// Identical math to r11 except x_mid is written as BF16 to workspace
// (halves write traffic); d_out untouched here.
// =====================================================================
__global__ __launch_bounds__(256, 3) void k_block1(
    const float* __restrict__ x,
    const float* __restrict__ ln1s, const float* __restrict__ ln1b,
    const unsigned short* __restrict__ qkvWp, const float* __restrict__ qkvBs,
    const float* __restrict__ relb,
    const unsigned short* __restrict__ projWp, const float* __restrict__ projB,
    unsigned short* __restrict__ xmid)
{
    __shared__ unsigned short sm[4 * 6144];   // 48 KB
    __shared__ float sbias[196];
    const int tid = threadIdx.x;
    const int wave = tid >> 6, lane = tid & 63;
    const int g = lane >> 4, m16 = lane & 15;
    if (tid < 196) sbias[tid] = relb[tid];
    const int win0 = blockIdx.x * 4;
    const int winM = win0 + wave;
    const int bbM = winM >> 8, whM = (winM >> 4) & 15, wnM = winM & 15;

    {
        float4 sc0 = *(const float4*)(ln1s + m16 * 8);
        float4 sc1 = *(const float4*)(ln1s + m16 * 8 + 4);
        float4 bi0 = *(const float4*)(ln1b + m16 * 8);
        float4 bi1 = *(const float4*)(ln1b + m16 * 8 + 4);
        #pragma unroll
        for (int it = 0; it < 4; ++it) {
            int tok = it * 4 + g;
            int ti = tok >> 2, tj = tok & 3;
            int hh = (whM * 4 + ti + 2) & 63, ww = (wnM * 4 + tj + 2) & 63;
            const float* xr = x + ((((size_t)bbM << 12) | (hh << 6) | ww) * 128) + m16 * 8;
            float4 v0 = *(const float4*)xr, v1 = *(const float4*)(xr + 4);
            float sum = v0.x + v0.y + v0.z + v0.w + v1.x + v1.y + v1.z + v1.w;
            float sq  = v0.x*v0.x + v0.y*v0.y + v0.z*v0.z + v0.w*v0.w
                      + v1.x*v1.x + v1.y*v1.y + v1.z*v1.z + v1.w*v1.w;
            #pragma unroll
            for (int m = 1; m < 16; m <<= 1) { sum += __shfl_xor(sum, m); sq += __shfl_xor(sq, m); }
            float mu = sum * 0.0078125f;
            float rstd = rsqrtf(sq * 0.0078125f - mu * mu + 1e-6f);
            us8 o;
            o[0] = f2b((v0.x - mu) * rstd * sc0.x + bi0.x);
            o[1] = f2b((v0.y - mu) * rstd * sc0.y + bi0.y);
            o[2] = f2b((v0.z - mu) * rstd * sc0.z + bi0.z);
            o[3] = f2b((v0.w - mu) * rstd * sc0.w + bi0.w);
            o[4] = f2b((v1.x - mu) * rstd * sc1.x + bi1.x);
            o[5] = f2b((v1.y - mu) * rstd * sc1.y + bi1.y);
            o[6] = f2b((v1.z - mu) * rstd * sc1.z + bi1.z);
            o[7] = f2b((v1.w - mu) * rstd * sc1.w + bi1.w);
            lds_st8(sm, wave * 12288 + tok * 256 + ((m16 * 16) ^ ((tok & 7) << 4)), o);
        }
    }
    __syncthreads();

    us8 afr[4][4];
    #pragma unroll
    for (int w = 0; w < 4; ++w)
        #pragma unroll
        for (int k = 0; k < 4; ++k)
            afr[w][k] = lds_ld8(sm, w * 12288 + m16 * 256 + ((k * 64 + g * 16) ^ ((m16 & 7) << 4)));
    __syncthreads();

    #pragma unroll
    for (int ct = 0; ct < 6; ++ct) {
        const unsigned short* bp = qkvWp + (size_t)((wave * 6 + ct) * 4) * 512 + lane * 8;
        us8 b0 = *(const us8*)(bp);
        us8 b1 = *(const us8*)(bp + 512);
        us8 b2 = *(const us8*)(bp + 1024);
        us8 b3 = *(const us8*)(bp + 1536);
        f32x4 acc[4] = {{0.f,0.f,0.f,0.f},{0.f,0.f,0.f,0.f},{0.f,0.f,0.f,0.f},{0.f,0.f,0.f,0.f}};
        #pragma unroll
        for (int w = 0; w < 4; ++w) {
            acc[w] = mfma16(afr[w][0], b0, acc[w]);
            acc[w] = mfma16(afr[w][1], b1, acc[w]);
            acc[w] = mfma16(afr[w][2], b2, acc[w]);
            acc[w] = mfma16(afr[w][3], b3, acc[w]);
        }
        const int c = wave * 96 + ct * 16 + m16;
        const float bias = qkvBs[c];
        const int s = c >> 7;
        const int rem = c & 127, hq = rem >> 5, hd = rem & 31;
        #pragma unroll
        for (int w = 0; w < 4; ++w) {
            const int base = w * 12288;
            if (s == 2) {
                us4 pk;
                #pragma unroll
                for (int jj = 0; jj < 4; ++jj) pk[jj] = f2b(acc[w][jj] + bias);
                *(us4*)((char*)sm + base + 8192 + hq * 1024 + hd * 32
                        + ((g ^ ((hd >> 2) & 3)) << 3)) = pk;
            } else {
                #pragma unroll
                for (int jj = 0; jj < 4; ++jj) {
                    int tok = g * 4 + jj;
                    int chunk = (hd >> 3) ^ ((tok >> 1) & 3);
                    *(unsigned short*)((char*)sm + base + s * 4096 + hq * 1024
                                       + tok * 64 + chunk * 16 + (hd & 7) * 2)
                        = f2b(acc[w][jj] + bias);
                }
            }
        }
    }
    __syncthreads();

    {
        const int base = wave * 12288;
        const int ti = m16 >> 2, tj = m16 & 3;
        const int hhq = whM * 4 + ti, wwq = wnM * 4 + tj;
        const int myid = (hhq < 60 ? 0 : (hhq < 62 ? 3 : 6)) + (wwq < 60 ? 0 : (wwq < 62 ? 1 : 2));
        const int qkswz = (g ^ ((m16 >> 1) & 3)) * 16;
        const int vswz  = (g ^ ((m16 >> 2) & 3)) << 3;
        f32x4 po[4][2];
        #pragma unroll
        for (int h = 0; h < 4; ++h) {
            us8 kf = lds_ld8(sm, base + 4096 + h * 1024 + m16 * 64 + qkswz);
            us8 qf = lds_ld8(sm, base +        h * 1024 + m16 * 64 + qkswz);
            f32x4 st = mfma16(kf, qf, (f32x4){0.f,0.f,0.f,0.f});
            float p[4];
            #pragma unroll
            for (int jj = 0; jj < 4; ++jj) {
                int kk = g * 4 + jj;
                int pi = kk >> 2, pj = kk & 3;
                int hhk = whM * 4 + pi, wwk = wnM * 4 + pj;
                int pid = (hhk < 60 ? 0 : (hhk < 62 ? 3 : 6)) + (wwk < 60 ? 0 : (wwk < 62 ? 1 : 2));
                float v = st[jj] + sbias[((ti - pi + 3) * 7 + (tj - pj + 3)) * 4 + h];
                p[jj] = (pid != myid) ? v - 100.f : v;
            }
            #pragma unroll
            for (int rep = 0; rep < 2; ++rep) {   // double softmax (faithful)
                float mx = fmaxf(fmaxf(p[0], p[1]), fmaxf(p[2], p[3]));
                mx = fmaxf(mx, __shfl_xor(mx, 16));
                mx = fmaxf(mx, __shfl_xor(mx, 32));
                float ssum = 0.f;
                #pragma unroll
                for (int jj = 0; jj < 4; ++jj) { p[jj] = __expf(p[jj] - mx); ssum += p[jj]; }
                ssum += __shfl_xor(ssum, 16);
                ssum += __shfl_xor(ssum, 32);
                float inv = 1.f / ssum;
                #pragma unroll
                for (int jj = 0; jj < 4; ++jj) p[jj] *= inv;
            }
            us4 pf;
            #pragma unroll
            for (int jj = 0; jj < 4; ++jj) pf[jj] = f2b(p[jj]);
            #pragma unroll
            for (int dh = 0; dh < 2; ++dh) {
                us4 vf = *(const us4*)((const char*)sm + base + 8192 + h * 1024
                                       + (dh * 16 + m16) * 32 + vswz);
                po[h][dh] = mfma16k16(vf, pf, (f32x4){0.f,0.f,0.f,0.f});
            }
        }
        #pragma unroll
        for (int h = 0; h < 4; ++h)
            #pragma unroll
            for (int dh = 0; dh < 2; ++dh) {
                us4 pk;
                #pragma unroll
                for (int jj = 0; jj < 4; ++jj) pk[jj] = f2b(po[h][dh][jj]);
                *(us4*)((char*)sm + base + m16 * 256
                        + ((h * 64 + dh * 32 + g * 8) ^ ((m16 & 7) << 4))) = pk;
            }
    }
    __syncthreads();

    {
        us8 cfr[4][4];
        #pragma unroll
        for (int w = 0; w < 4; ++w)
            #pragma unroll
            for (int k = 0; k < 4; ++k)
                cfr[w][k] = lds_ld8(sm, w * 12288 + m16 * 256 + ((k * 64 + g * 16) ^ ((m16 & 7) << 4)));
        #pragma unroll
        for (int ct = 0; ct < 2; ++ct) {
            const unsigned short* bp = projWp + (size_t)((wave * 2 + ct) * 4) * 512 + lane * 8;
            us8 b0 = *(const us8*)(bp);
            us8 b1 = *(const us8*)(bp + 512);
            us8 b2 = *(const us8*)(bp + 1024);
            us8 b3 = *(const us8*)(bp + 1536);
            const int c = wave * 32 + ct * 16 + m16;
            const float pb = projB[c];
            #pragma unroll
            for (int w = 0; w < 4; ++w) {
                f32x4 acc = {0.f, 0.f, 0.f, 0.f};
                acc = mfma16(cfr[w][0], b0, acc);
                acc = mfma16(cfr[w][1], b1, acc);
                acc = mfma16(cfr[w][2], b2, acc);
                acc = mfma16(cfr[w][3], b3, acc);
                const int winw = win0 + w;
                const int bb = winw >> 8, wh = (winw >> 4) & 15, wn = winw & 15;
                #pragma unroll
                for (int jj = 0; jj < 4; ++jj) {
                    int tok = g * 4 + jj;
                    int hh3 = (wh * 4 + (tok >> 2) + 2) & 63;
                    int ww3 = (wn * 4 + (tok & 3) + 2) & 63;
                    size_t t = (((size_t)bb << 12) | (hh3 << 6) | ww3);
                    xmid[t * 128 + c] = f2b(acc[jj] + pb + x[t * 128 + c]);
                }
            }
        }
    }
}

// =====================================================================
// K2 v9: LN2 + FC1 + GELU + FC2 + residual. Reads BF16 x_mid (halved
// read burst); epilogue re-reads x_mid (L2-hot) and STREAMS out
// (write-only, no RMW). Structure otherwise identical to r11.
// =====================================================================
__global__ __launch_bounds__(256, 3) void k_block2(
    const unsigned short* __restrict__ xmid,
    float* __restrict__ out,
    const float* __restrict__ ln2s, const float* __restrict__ ln2b,
    const unsigned short* __restrict__ wPack,
    const float* __restrict__ fc1B, const float* __restrict__ fc2B)
{
    __shared__ unsigned short smem[24576];   // 48KB: [0,8K) scratch shorts, [8K,24K) wbuf
    const int tid = threadIdx.x;
    const int wave = tid >> 6, lane = tid & 63;
    const int g = lane >> 4, m16 = lane & 15;
    const size_t r0 = (size_t)blockIdx.x * 128;
    unsigned short* scr = &smem[wave * 2048];

    // ---- stage pair 0 into buf0 FIRST (latency hides under LN) ----
    #pragma unroll
    for (int sub = 0; sub < 4; ++sub) {
        const unsigned short* src = wPack + sub * 2048 + tid * 8;
        unsigned short* dst = &smem[8192 + sub * 2048 + wave * 512];
#if __has_builtin(__builtin_amdgcn_global_load_lds)
        __builtin_amdgcn_global_load_lds(
            (const __attribute__((address_space(1))) void*)src,
            (__attribute__((address_space(3))) void*)dst, 16, 0, 0);
#else
        *(us8*)(dst + lane * 8) = *(const us8*)src;
#endif
    }

    // ---- LN2: 2 passes of 16 rows, bf16 input, wave-private scratch ----
    float scv[8], biv[8];
    {
        float4 s0 = *(const float4*)(ln2s + m16 * 8);
        float4 s1 = *(const float4*)(ln2s + m16 * 8 + 4);
        float4 b0 = *(const float4*)(ln2b + m16 * 8);
        float4 b1 = *(const float4*)(ln2b + m16 * 8 + 4);
        scv[0]=s0.x; scv[1]=s0.y; scv[2]=s0.z; scv[3]=s0.w;
        scv[4]=s1.x; scv[5]=s1.y; scv[6]=s1.z; scv[7]=s1.w;
        biv[0]=b0.x; biv[1]=b0.y; biv[2]=b0.z; biv[3]=b0.w;
        biv[4]=b1.x; biv[5]=b1.y; biv[6]=b1.z; biv[7]=b1.w;
    }
    us8 bx[2][4];
    #pragma unroll
    for (int rt = 0; rt < 2; ++rt) {
        #pragma unroll
        for (int it = 0; it < 4; ++it) {
            int lr = it * 4 + g;
            us8 u = *(const us8*)(xmid + (r0 + wave * 32 + rt * 16 + lr) * 128 + m16 * 8);
            float f[8];
            #pragma unroll
            for (int q = 0; q < 8; ++q) f[q] = b2f(u[q]);
            float sum = 0.f, sq = 0.f;
            #pragma unroll
            for (int q = 0; q < 8; ++q) { sum += f[q]; sq += f[q] * f[q]; }
            #pragma unroll
            for (int m = 1; m < 16; m <<= 1) { sum += __shfl_xor(sum, m); sq += __shfl_xor(sq, m); }
            float mu = sum * 0.0078125f;
            float rstd = rsqrtf(sq * 0.0078125f - mu * mu + 1e-6f);
            us8 o;
            #pragma unroll
            for (int q = 0; q < 8; ++q) o[q] = f2b((f[q] - mu) * rstd * scv[q] + biv[q]);
            lds_st8(scr, lr * 256 + ((m16 * 16) ^ ((lr & 7) << 4)), o);
        }
        // wave-local read-back (lgkm-ordered, no barrier)
        #pragma unroll
        for (int kk = 0; kk < 4; ++kk)
            bx[rt][kk] = lds_ld8(scr, m16 * 256 + ((kk * 64 + g * 16) ^ ((m16 & 7) << 4)));
    }
    __syncthreads();          // pair-0 staging complete + all waves ready

    f32x4 accO[2][8];
    #pragma unroll
    for (int rt = 0; rt < 2; ++rt)
        #pragma unroll
        for (int co = 0; co < 8; ++co) accO[rt][co] = (f32x4){0.f, 0.f, 0.f, 0.f};

    for (int p = 0; p < 16; ++p) {
        if (p < 15) {
            #pragma unroll
            for (int sub = 0; sub < 4; ++sub) {
                const unsigned short* src = wPack + (p + 1) * 8192 + sub * 2048 + tid * 8;
                unsigned short* dst = &smem[8192 + ((p + 1) & 1) * 8192 + sub * 2048 + wave * 512];
#if __has_builtin(__builtin_amdgcn_global_load_lds)
                __builtin_amdgcn_global_load_lds(
                    (const __attribute__((address_space(1))) void*)src,
                    (__attribute__((address_space(3))) void*)dst, 16, 0, 0);
#else
                *(us8*)(dst + lane * 8) = *(const us8*)src;
#endif
            }
        }
        const char* wb = (const char*)&smem[8192 + (p & 1) * 8192];
        // FC1^T halves (aw frags shared across both row-tiles)
        f32x4 hA0 = {0.f,0.f,0.f,0.f}, hA1 = {0.f,0.f,0.f,0.f};
        #pragma unroll
        for (int kk = 0; kk < 4; ++kk) {
            us8 aw = *(const us8*)(wb + kk * 1024 + lane * 16);
            hA0 = mfma16(aw, bx[0][kk], hA0);
            hA1 = mfma16(aw, bx[1][kk], hA1);
        }
        f32x4 hB0 = {0.f,0.f,0.f,0.f}, hB1 = {0.f,0.f,0.f,0.f};
        #pragma unroll
        for (int kk = 0; kk < 4; ++kk) {
            us8 aw = *(const us8*)(wb + 4096 + kk * 1024 + lane * 16);
            hB0 = mfma16(aw, bx[0][kk], hB0);
            hB1 = mfma16(aw, bx[1][kk], hB1);
        }
        float4 bA = *(const float4*)(fc1B + p * 32 + g * 8);
        float4 bB = *(const float4*)(fc1B + p * 32 + g * 8 + 4);
        us8 pa0, pa1;
        #pragma unroll
        for (int jj = 0; jj < 4; ++jj) {
            float v0 = hA0[jj] + ((const float*)&bA)[jj];
            float z0 = v0 + 0.044715f * v0 * v0 * v0;
            pa0[jj] = f2b(v0 * __builtin_amdgcn_rcpf(1.f + __builtin_amdgcn_exp2f(-2.3022082f * z0)));
            float w0 = hB0[jj] + ((const float*)&bB)[jj];
            float y0 = w0 + 0.044715f * w0 * w0 * w0;
            pa0[4 + jj] = f2b(w0 * __builtin_amdgcn_rcpf(1.f + __builtin_amdgcn_exp2f(-2.3022082f * y0)));
            float v1 = hA1[jj] + ((const float*)&bA)[jj];
            float z1 = v1 + 0.044715f * v1 * v1 * v1;
            pa1[jj] = f2b(v1 * __builtin_amdgcn_rcpf(1.f + __builtin_amdgcn_exp2f(-2.3022082f * z1)));
            float w1 = hB1[jj] + ((const float*)&bB)[jj];
            float y1 = w1 + 0.044715f * w1 * w1 * w1;
            pa1[4 + jj] = f2b(w1 * __builtin_amdgcn_rcpf(1.f + __builtin_amdgcn_exp2f(-2.3022082f * y1)));
        }
        // FC2: 8 K=32 MFMAs per row-tile, bw frag shared across tiles
        #pragma unroll
        for (int co = 0; co < 8; ++co) {
            us8 bw = *(const us8*)(wb + 8192 + co * 1024 + lane * 16);
            accO[0][co] = mfma16(pa0, bw, accO[0][co]);
            accO[1][co] = mfma16(pa1, bw, accO[1][co]);
        }
        __syncthreads();
    }

    // ---- epilogue: bias + bf16 residual (L2-hot re-read) -> streamed out ----
    #pragma unroll
    for (int rt = 0; rt < 2; ++rt)
        #pragma unroll
        for (int co = 0; co < 8; ++co) {
            int col = co * 16 + m16;
            float b2v = fc2B[col];
            #pragma unroll
            for (int jj = 0; jj < 4; ++jj) {
                size_t row = r0 + wave * 32 + rt * 16 + g * 4 + jj;
                out[row * 128 + col] = accO[rt][co][jj] + b2v + b2f(xmid[row * 128 + col]);
            }
        }
}

// ---------- launch ----------
extern "C" void kernel_launch(void* const* d_in, const int* in_sizes, int n_in,
                              void* d_out, int out_size, void* d_ws, size_t ws_size,
                              hipStream_t stream) {
    const float* x        = (const float*)d_in[0];
    const float* ln1_s    = (const float*)d_in[1];
    const float* ln1_b    = (const float*)d_in[2];
    const float* qkv_w    = (const float*)d_in[3];
    const float* qkv_b    = (const float*)d_in[4];
    const float* rel_bias = (const float*)d_in[5];
    const float* proj_w   = (const float*)d_in[6];
    const float* proj_b   = (const float*)d_in[7];
    const float* ln2_s    = (const float*)d_in[8];
    const float* ln2_b    = (const float*)d_in[9];
    const float* fc1_w    = (const float*)d_in[10];
    const float* fc1_b    = (const float*)d_in[11];
    const float* fc2_w    = (const float*)d_in[12];
    const float* fc2_b    = (const float*)d_in[13];
    float* out = (float*)d_out;
    char* ws = (char*)d_ws;

    unsigned short* qkv_wp  = (unsigned short*)(ws);             // 96KB packed qkv frags
    unsigned short* proj_wp = (unsigned short*)(ws + 98304);     // 32KB packed proj frags
    unsigned short* wpack   = (unsigned short*)(ws + 131072);    // 256KB packed MLP (16x16KB)
    float*          qkv_bs  = (float*)(ws + 393216);             // 1.5KB scaled qkv bias
    unsigned short* xmid    = (unsigned short*)(ws + 524288);    // 64MB bf16 x_mid

    k_pack_qkvw<<<192, 256, 0, stream>>>(qkv_w, qkv_wp);
    k_scale_qkvb<<<2, 256, 0, stream>>>(qkv_b, qkv_bs);
    k_pack_projw<<<64, 256, 0, stream>>>(proj_w, proj_wp);
    k_pack_mlp<<<512, 256, 0, stream>>>(fc1_w, fc2_w, wpack);

    k_block1<<<4096, 256, 0, stream>>>(x, ln1_s, ln1_b, qkv_wp, qkv_bs, rel_bias,
                                       proj_wp, proj_b, xmid);
    k_block2<<<2048, 256, 0, stream>>>(xmid, out, ln2_s, ln2_b, wpack, fc1_b, fc2_b);
}